// Round 11
// baseline (864.496 us; speedup 1.0000x reference)
//
#include <hip/hip_runtime.h>
#include <hip/hip_bf16.h>

// RNN: B=4096, T=1024, H=40, K=41. fp32 compute & state (dtype autodetected).
// Round-21: register-resident weights via demand<=budget + asm pin.
// R20 post-mortem: cheap packed-fp32 reloads changed NOTHING (854 vs 816/823)
// -> with R19 (barriers irrelevant) + R11 (conflicts irrelevant), the wall is
// WEIGHT-OPERAND DELIVERY BANDWIDTH: 16 els/CU x 4961 floats x 4B ~= 317 KB
// must flow L1->VALU per step (VGPR=60, nothing resident). At ~160 B/cyc/CU
// that's ~2000 cyc/step = measured 2001, invariant across R10-R20. Only the
// register file has the bandwidth. Why pins failed before: demand was always
// > budget (R12: 163 floats; R20: 80 + 20-reg read window + scalars ~= 130 >
// 128) -> allocator parked everything. Fix the arithmetic, then pin:
//  (1) stream hv/av one f4 at a time (live window 4 regs, not 20);
//  (2) scalars unpinned (8 cheap remat loads/step);
//  (3) peak demand ~= 80 pinned + 4 window + 6 acc + ~20 misc ~= 112 <= 128;
//  (4) amdgpu_waves_per_eu(4,4): budget 128 = residency (4096 blks = 4/EU);
//  (5) ONE empty asm "+v" on 20 f4 after load: asm-defined => NOT remat-able.
// Everything else identical to R20 (structure, math, order -> same absmax).
// Decisive counter: VGPR_Count >= 115 means the pin held; dur ~380-550.

#define B_SZ 4096
#define T_SZ 1024
#define HID  40
#define WSTRIDE 88   // floats per lane slice in ws (352 B, 16B-aligned)

typedef unsigned short u16;
typedef unsigned int   u32;
typedef float f2 __attribute__((ext_vector_type(2)));
typedef float f4 __attribute__((ext_vector_type(4)));

// Zero-cost single-wave "barrier" (proven R19: LDS ops of one wave are
// processed in program order; only forbid COMPILER reordering).
#define WFENCE() do {                      \
    asm volatile("" ::: "memory");         \
    __builtin_amdgcn_wave_barrier();       \
    asm volatile("" ::: "memory");         \
  } while (0)

__device__ __forceinline__ float bf2f(u16 v) {
  union { u32 u; float f; } c; c.u = ((u32)v) << 16; return c.f;
}

// Proven rounds 3-20: true-bf16 weights all have |w| <= 1/sqrt(41) ~ 0.156;
// fp32 data read as bf16 halfwords exceeds 0.2 with P ~ 1-1e-10.
__device__ __forceinline__ bool detect_bf16(const void* w) {
  const u16* p = (const u16*)w;
  bool bf = true;
  for (int i = 0; i < 64; ++i) {
    float f = bf2f(p[i]);
    if (!(fabsf(f) <= 0.2f)) bf = false;
  }
  return bf;
}

__device__ __forceinline__ float ldgr(bool bf, const void* p, long i) {
  return bf ? bf2f(((const u16*)p)[i]) : ((const float*)p)[i];
}

// Partner value from lane^1 (quad_perm [1,0,3,2]). VALU pipe, no LDS.
__device__ __forceinline__ float pair_other(float x) {
  return __int_as_float(__builtin_amdgcn_update_dpp(
      0, __float_as_int(x), 0xB1, 0xF, 0xF, true));
}

// ---- Pack kernel: per-lane fp32 weight slices into ws (R20, unchanged) ----
__global__ __launch_bounds__(64)
void pack_weights(const void* __restrict__ h2h_w1, const void* __restrict__ h2h_b1,
                  const void* __restrict__ h2h_w2, const void* __restrict__ h2h_b2,
                  const void* __restrict__ h2o_w1, const void* __restrict__ h2o_b1,
                  const void* __restrict__ h2o_w2, const void* __restrict__ h2o_b2,
                  float* __restrict__ ws) {
  const bool bf  = detect_bf16(h2h_w1);
  const int lane = threadIdx.x;       // 0..63
  const int kh   = lane & 1;
  const int w    = lane >> 1;
  const int koff = kh * 20;

  const bool hh01 = (2 * w < HID);
  const void* p01 = hh01 ? h2h_w1 : h2o_w1;
  const long  jr0 = hh01 ? 2 * w : 2 * w - HID;
  const bool  s2A = (w >= 16);
  const void* p2  = s2A ? h2o_w1 : h2h_w2;
  const long  o2  = s2A ? ((long)(8 + w) * 41 + 1 + koff) : ((long)w * HID + koff);
  const bool  isOut = (w == 24);
  const void* p3  = isOut ? h2o_w2 : h2h_w2;
  const long  o3  = isOut ? (long)koff : ((long)(16 + (w < 24 ? w : 0)) * HID + koff);

  float* dst = ws + (long)lane * WSTRIDE;
  for (int i = 0; i < 20; ++i) {
    dst[i]      = ldgr(bf, p01, jr0 * 41 + 1 + koff + i);
    dst[20 + i] = ldgr(bf, p01, (jr0 + 1) * 41 + 1 + koff + i);
    dst[40 + i] = ldgr(bf, p2, o2 + i);
    dst[60 + i] = ldgr(bf, p3, o3 + i);
  }
  float wu0 = 0, wu1 = 0, wu2 = 0, ba0 = 0, ba1 = 0, ba2 = 0, bb2 = 0, bb3 = 0;
  if (kh == 0) {
    const void* b1p = hh01 ? h2h_b1 : h2o_b1;
    wu0 = ldgr(bf, p01, jr0 * 41);
    wu1 = ldgr(bf, p01, (jr0 + 1) * 41);
    ba0 = ldgr(bf, b1p, jr0);
    ba1 = ldgr(bf, b1p, jr0 + 1);
    if (s2A) { wu2 = ldgr(bf, h2o_w1, (long)(8 + w) * 41); ba2 = ldgr(bf, h2o_b1, 8 + w); }
    else     { bb2 = ldgr(bf, h2h_b2, w); }
    if (isOut)       bb3 = ldgr(bf, h2o_b2, 0);
    else if (w < 24) bb3 = ldgr(bf, h2h_b2, 16 + w);
  }
  dst[80] = wu0; dst[81] = wu1; dst[82] = wu2; dst[83] = ba0;
  dst[84] = ba1; dst[85] = ba2; dst[86] = bb2; dst[87] = bb3;
}

template <bool BF>
__global__ __launch_bounds__(64)
__attribute__((amdgpu_waves_per_eu(4, 4)))   // budget 128 = residency (4/EU)
void rnn_kernel(const void* __restrict__ inp, const void* __restrict__ h2h_w1,
                const float* __restrict__ ws, void* __restrict__ out) {
  __shared__ __align__(16) float sH[44];  // hidden state h[0..39]
  __shared__ __align__(16) float sA[84];  // L1 acts: a-rows [0..39], o-rows [40..79]

  if (detect_bf16(h2h_w1) != BF) return;  // wrong-dtype instantiation exits

  const int lane = threadIdx.x & 63;
  const int kh   = lane & 1;          // K-half: 0 -> u + k0..19, 1 -> k20..39
  const int w    = lane >> 1;         // worker 0..31
  const int koff = kh * 20;
  const bool s2A   = (w >= 16);
  const bool isOut = (w == 24);

  // ---- Weights: 80 floats = 20 f4, loaded once, then HARD-PINNED. ----
  f4 wq[20];
  {
    const f4* src = (const f4*)(ws + (long)lane * WSTRIDE);
#pragma unroll
    for (int i = 0; i < 20; ++i) wq[i] = src[i];
  }
  // asm-defined values cannot be remat'd as loads; demand fits budget so
  // there is no pressure reason to park them in AGPRs either.
  asm volatile("" :
      "+v"(wq[0]),  "+v"(wq[1]),  "+v"(wq[2]),  "+v"(wq[3]),  "+v"(wq[4]),
      "+v"(wq[5]),  "+v"(wq[6]),  "+v"(wq[7]),  "+v"(wq[8]),  "+v"(wq[9]),
      "+v"(wq[10]), "+v"(wq[11]), "+v"(wq[12]), "+v"(wq[13]), "+v"(wq[14]),
      "+v"(wq[15]), "+v"(wq[16]), "+v"(wq[17]), "+v"(wq[18]), "+v"(wq[19]));
  const f2* wp = (const f2*)wq;   // slot s, pair i -> wp[10*s + i]

  // Scalars: UNPINNED (8 cheap remat loads/step keeps peak demand low).
  const float* wsc = ws + (long)lane * WSTRIDE + 80;
  const float wu0 = wsc[0], wu1 = wsc[1], wu2 = wsc[2], ba0 = wsc[3];
  const float ba1 = wsc[4], ba2 = wsc[5], bb2 = wsc[6], bb3 = wsc[7];

  for (int i = lane; i < 44; i += 64) sH[i] = 0.f;
  WFENCE();   // single wave: zeroing writes ordered before first reads

  const long base = (long)blockIdx.x * T_SZ;   // 1 el per block
  float u_cur = BF ? bf2f(((const u16*)inp)[base]) : ((const float*)inp)[base];

  const f4* hp = (const f4*)(&sH[koff]);                     // broadcast
  const f4* ap = (const f4*)(&sA[isOut ? 40 + koff : koff]); // broadcast (2 addrs)
  const bool wrA2 = s2A && (kh == 0);
  const bool wr2  = (!s2A) && (kh == 0);        // w<16: new h[w]
  const bool wr3  = (w < 24) && (kh == 0);      // new h[16+w]
  const bool wrY  = isOut && (kh == 0);

  for (int t = 0; t < T_SZ; ++t) {
    const float u_nxt = (t + 1 < T_SZ)
        ? (BF ? bf2f(((const u16*)inp)[base + t + 1]) : ((const float*)inp)[base + t + 1])
        : 0.f;

    // ---------- Phase A: L1 rows (slots 0,1,2) vs state ----------
    // Stream the state one f4 at a time: live window = 4 regs, not 20.
    {
      f2 a0 = {0.f, 0.f}, a1 = {0.f, 0.f}, a2 = {0.f, 0.f};
#pragma unroll
      for (int m = 0; m < 5; ++m) {
        const f4 h4 = hp[m];
        const f2 hA = {h4.x, h4.y}, hB = {h4.z, h4.w};
        a0 = hA * wp[2 * m]      + a0;
        a0 = hB * wp[2 * m + 1]  + a0;
        a1 = hA * wp[10 + 2 * m] + a1;
        a1 = hB * wp[11 + 2 * m] + a1;
        a2 = hA * wp[20 + 2 * m] + a2;   // garbage for w<16 (not written)
        a2 = hB * wp[21 + 2 * m] + a2;
      }
      const float v0 = fmaf(u_cur, wu0, ba0) + a0.x + a0.y;
      const float v1 = fmaf(u_cur, wu1, ba1) + a1.x + a1.y;
      const float v2 = fmaf(u_cur, wu2, ba2) + a2.x + a2.y;
      const float t0 = v0 + pair_other(v0);
      const float t1 = v1 + pair_other(v1);
      const float t2 = v2 + pair_other(v2);
      if (kh == 0) {
        f2 act01;
        act01.x = fmaxf(t0, 0.01f * t0);
        act01.y = fmaxf(t1, 0.01f * t1);
        *(f2*)(&sA[2 * w]) = act01;            // b64, 2-way bank (free)
      }
      if (wrA2) sA[48 + w] = fmaxf(t2, 0.01f * t2);   // o-acts rows 64..79
    }
    WFENCE();   // in-wave DS order: acts written before phase-B reads

    // ---------- Phase B: L2 rows + output (slots 2,3) vs acts ----------
    {
      f2 b2 = {0.f, 0.f}, b3 = {0.f, 0.f};
#pragma unroll
      for (int m = 0; m < 5; ++m) {
        const f4 a4 = ap[m];
        const f2 aA = {a4.x, a4.y}, aB = {a4.z, a4.w};
        b2 = aA * wp[20 + 2 * m] + b2;   // garbage for w>=16 (not written)
        b2 = aB * wp[21 + 2 * m] + b2;
        b3 = aA * wp[30 + 2 * m] + b3;   // garbage for w>24 (not written)
        b3 = aB * wp[31 + 2 * m] + b3;
      }
      const float v2 = bb2 + b2.x + b2.y;
      const float v3 = bb3 + b3.x + b3.y;
      const float t2 = v2 + pair_other(v2);
      const float t3 = v3 + pair_other(v3);
      if (wr2) sH[w] = t2;                     // new h[0..15]
      if (wr3) sH[16 + w] = t3;                // new h[16..39]
      if (wrY) {                               // y(t)
        if (BF) ((__hip_bfloat16*)out)[base + t] = __float2bfloat16(t3);
        else    ((float*)out)[base + t] = t3;
      }
    }
    WFENCE();   // acts consumed before next step's phase-A overwrites

    u_cur = u_nxt;
  }
}

extern "C" void kernel_launch(void* const* d_in, const int* in_sizes, int n_in,
                              void* d_out, int out_size, void* d_ws, size_t ws_size,
                              hipStream_t stream) {
  (void)in_sizes; (void)n_in; (void)out_size;
  if (ws_size < (size_t)(64 * WSTRIDE * sizeof(float))) return;  // need 22.5 KB
  float* ws = (float*)d_ws;
  pack_weights<<<dim3(1), dim3(64), 0, stream>>>(
      d_in[1], d_in[2], d_in[3], d_in[4],
      d_in[5], d_in[6], d_in[7], d_in[8], ws);
  rnn_kernel<false><<<dim3(B_SZ), dim3(64), 0, stream>>>(
      d_in[0], d_in[1], ws, d_out);
  rnn_kernel<true><<<dim3(B_SZ), dim3(64), 0, stream>>>(
      d_in[0], d_in[1], ws, d_out);
}